// Round 7
// baseline (219.374 us; speedup 1.0000x reference)
//
#include <hip/hip_runtime.h>
#include <hip/hip_bf16.h>
#include <math.h>

// Problem constants (BN, N, FIN, FO, H) from the reference
#define BN_   4
#define NN_   2048
#define FIN_  128
#define FO_   64
#define H_    4
#define D_    256   // FO*H

typedef __attribute__((ext_vector_type(8))) short bf16x8;   // 8 bf16 = 4 VGPRs
typedef __attribute__((ext_vector_type(4))) float floatx4;  // MFMA C/D frag

#define LOG2E 1.4426950408889634f

#if __has_builtin(__builtin_amdgcn_exp2f)
#define EXP2(x) __builtin_amdgcn_exp2f(x)
#else
#define EXP2(x) exp2f(x)
#endif

__device__ __forceinline__ float bf2f(short u) {
    union { unsigned int i; float f; } v;
    v.i = ((unsigned int)(unsigned short)u) << 16;
    return v.f;
}
__device__ __forceinline__ short f2bf(float f) {
    union { float f; unsigned int u; } v; v.f = f;
    unsigned int r = v.u + 0x7fffu + ((v.u >> 16) & 1u);  // RNE
    return (short)(unsigned short)(r >> 16);
}

// pack two floats to two bf16 (RNE) in one dword; elem0 in low 16 bits
#if defined(__BF16_MANT_DIG__)
typedef __bf16 bfr2 __attribute__((ext_vector_type(2)));
__device__ __forceinline__ unsigned int pack_bf16(float a, float b) {
    union { bfr2 h; unsigned int u; } v;
    v.h = (bfr2){(__bf16)a, (__bf16)b};   // gfx950: v_cvt_pk_bf16_f32
    return v.u;
}
#else
__device__ __forceinline__ unsigned int pack_bf16(float a, float b) {
    return ((unsigned int)(unsigned short)f2bf(a)) |
           (((unsigned int)(unsigned short)f2bf(b)) << 16);
}
#endif

// load 8 consecutive fp32 and round to a bf16x8 MFMA fragment
__device__ __forceinline__ bf16x8 load8f(const float* __restrict__ p) {
    floatx4 a = *(const floatx4*)p;
    floatx4 b = *(const floatx4*)(p + 4);
    union { bf16x8 v; unsigned int u[4]; } r;
    r.u[0] = pack_bf16(a[0], a[1]);
    r.u[1] = pack_bf16(a[2], a[3]);
    r.u[2] = pack_bf16(b[0], b[1]);
    r.u[3] = pack_bf16(b[2], b[3]);
    return r.v;
}

// ---------------------------------------------------------------------------
// Kernel 1: PT[b_rel][h][f][j] = sum_c x[b,j,c] * W_proj[f*H+h, c]  (bf16)
// PT slab per batch: row index (b_rel*D_ + h*64 + f), j contiguous.
// MFMA 16x16x32 bf16: A[m=lane&15][k=quad*8+e]=W rows, B[n=lane&15][k]=x.
// ---------------------------------------------------------------------------
__global__ __launch_bounds__(256) void proj_kernel(
    const float* __restrict__ x,      // (BN, NN, FIN) fp32
    const float* __restrict__ wproj,  // (D, FIN) fp32
    short* __restrict__ pt,           // (nb*D, NN) bf16 slabs
    int b0)
{
    const int tid  = threadIdx.x;
    const int wave = tid >> 6;
    const int lane = tid & 63;
    const int l16  = lane & 15;
    const int quad = lane >> 4;

    const int b_rel = blockIdx.z;
    const int b  = b0 + b_rel;
    const int h  = blockIdx.y;            // D_/64 == H_, so y-block == head
    const int d0 = h * 64;
    const int j0 = blockIdx.x * 256 + wave * 64;

    floatx4 acc[4][4];
#pragma unroll
    for (int mi = 0; mi < 4; ++mi)
#pragma unroll
        for (int nj = 0; nj < 4; ++nj)
            acc[mi][nj] = (floatx4){0.f, 0.f, 0.f, 0.f};

#pragma unroll
    for (int kc = 0; kc < 4; ++kc) {
        const int c = kc * 32 + quad * 8;
        bf16x8 afr[4], bfr[4];
#pragma unroll
        for (int mi = 0; mi < 4; ++mi) {
            int f = (d0 + mi * 16 + l16) & 63;
            int srow = f * H_ + h;                // W_proj row (flat d = f*H+h)
            afr[mi] = load8f(wproj + srow * FIN_ + c);
        }
#pragma unroll
        for (int nj = 0; nj < 4; ++nj) {
            int j = j0 + nj * 16 + l16;
            bfr[nj] = load8f(x + ((size_t)b * NN_ + j) * FIN_ + c);
        }
#pragma unroll
        for (int mi = 0; mi < 4; ++mi)
#pragma unroll
            for (int nj = 0; nj < 4; ++nj)
                acc[mi][nj] = __builtin_amdgcn_mfma_f32_16x16x32_bf16(
                    afr[mi], bfr[nj], acc[mi][nj], 0, 0, 0);
    }

    // C/D layout: col(n=j) = lane&15, row(m=d') = quad*4 + reg
#pragma unroll
    for (int mi = 0; mi < 4; ++mi) {
#pragma unroll
        for (int r = 0; r < 4; ++r) {
            int dp = d0 + mi * 16 + quad * 4 + r;
            size_t base = ((size_t)b_rel * D_ + dp) * NN_;
#pragma unroll
            for (int nj = 0; nj < 4; ++nj) {
                int j = j0 + nj * 16 + l16;
                pt[base + j] = f2bf(acc[mi][nj][r]);
            }
        }
    }
}

// ---------------------------------------------------------------------------
// Kernel 2: fused attention, I-tile = 64. Block = 8 waves on the SAME
// (b, head, 64-row i-tile); waves split j (256 each). Each wave holds 4
// 16-row A-fragments (weights) sharing the same pt B-fragments (4x reuse).
// s_src / s_tgt are recomputed in-block from PT (quad-butterfly dot over f)
// -> no s workspace -> single pass. Max-free softmax (bounded scores).
// Epilogue: 4 chunks of the 8-wave LDS reduction. Output fp32.
// ---------------------------------------------------------------------------
#define RSTRIDE 65   // LDS row stride (pad +1 col to break bank alignment)
#define WSLOT   (RSTRIDE * 16 + 16)   // 1056 floats per wave slot

__global__ __launch_bounds__(512, 4) void attn_kernel(
    const float* __restrict__ adj,    // (BN, NN, NN) fp32
    const short* __restrict__ pt,     // (nb*D, NN) bf16
    const float* __restrict__ ssrc,   // (H, FO) fp32
    const float* __restrict__ stgt,   // (H, FO) fp32
    const float* __restrict__ bias,   // (D,) fp32
    float* __restrict__ out,          // (BN, NN, D) fp32
    int b0)
{
    __shared__ float red[8][WSLOT];   // 33792 B (reduction scratch)
    __shared__ float st_lds[8][256];  // per-wave s_tgt slice (8 KiB)
    __shared__ float ss_lds[64];      // s_src for the i-tile

    const int tid  = threadIdx.x;
    const int w    = tid >> 6;        // wave = j-slice
    const int lane = tid & 63;
    const int l16  = lane & 15;
    const int quad = lane >> 4;

    const int b_rel = blockIdx.z;
    const int b  = b0 + b_rel;
    const int h  = blockIdx.y;
    const int i0 = blockIdx.x * 64;

    const short* pt_bh = pt + ((size_t)b_rel * D_ + h * FO_) * NN_;

    // my 4 f-rows' score weights (f = K*16 + l16)
    float stw[4], ssw[4];
#pragma unroll
    for (int K = 0; K < 4; ++K) {
        stw[K] = stgt[h * FO_ + K * 16 + l16];
        ssw[K] = ssrc[h * FO_ + K * 16 + l16];
    }

    // ---- preamble A: s_tgt for this wave's 256-j slice -> st_lds[w] ----
#pragma unroll
    for (int pj = 0; pj < 8; ++pj) {
        const int c = w * 256 + pj * 32 + quad * 8;
        bf16x8 p0 = *(const bf16x8*)(pt_bh + (size_t)(l16) * NN_ + c);
        bf16x8 p1 = *(const bf16x8*)(pt_bh + (size_t)(16 + l16) * NN_ + c);
        bf16x8 p2 = *(const bf16x8*)(pt_bh + (size_t)(32 + l16) * NN_ + c);
        bf16x8 p3 = *(const bf16x8*)(pt_bh + (size_t)(48 + l16) * NN_ + c);
#pragma unroll
        for (int e = 0; e < 8; ++e) {
            float t = stw[0] * bf2f(p0[e]) + stw[1] * bf2f(p1[e])
                    + stw[2] * bf2f(p2[e]) + stw[3] * bf2f(p3[e]);
            t += __shfl_xor(t, 1, 64); t += __shfl_xor(t, 2, 64);
            t += __shfl_xor(t, 4, 64); t += __shfl_xor(t, 8, 64);
            if (l16 == 0) st_lds[w][pj * 32 + quad * 8 + e] = t;
        }
    }

    // ---- preamble B: s_src for the 64 i-rows (waves 0,1) -> ss_lds ----
    if (w < 2) {
        const int c = i0 + w * 32 + quad * 8;
        bf16x8 p0 = *(const bf16x8*)(pt_bh + (size_t)(l16) * NN_ + c);
        bf16x8 p1 = *(const bf16x8*)(pt_bh + (size_t)(16 + l16) * NN_ + c);
        bf16x8 p2 = *(const bf16x8*)(pt_bh + (size_t)(32 + l16) * NN_ + c);
        bf16x8 p3 = *(const bf16x8*)(pt_bh + (size_t)(48 + l16) * NN_ + c);
#pragma unroll
        for (int e = 0; e < 8; ++e) {
            float t = ssw[0] * bf2f(p0[e]) + ssw[1] * bf2f(p1[e])
                    + ssw[2] * bf2f(p2[e]) + ssw[3] * bf2f(p3[e]);
            t += __shfl_xor(t, 1, 64); t += __shfl_xor(t, 2, 64);
            t += __shfl_xor(t, 4, 64); t += __shfl_xor(t, 8, 64);
            if (l16 == 0) ss_lds[w * 32 + quad * 8 + e] = t;
        }
    }
    __syncthreads();

    // per-lane s_src for my 4 sub-tiles (row = sub*16 + l16)
    float ssv[4];
#pragma unroll
    for (int sub = 0; sub < 4; ++sub)
        ssv[sub] = ss_lds[sub * 16 + l16];

    // pre-offset global bases (wave j-slice + quad offset folded in)
    const int qo = quad * 8;
    const float* adj_s[4];
#pragma unroll
    for (int sub = 0; sub < 4; ++sub)
        adj_s[sub] = adj + ((size_t)b * NN_ + i0 + sub * 16 + l16) * NN_ + w * 256 + qo;
    const short* ptr_f[4];
#pragma unroll
    for (int K = 0; K < 4; ++K)
        ptr_f[K] = pt_bh + (size_t)(K * 16 + l16) * NN_ + w * 256 + qo;
    const float* stp = &st_lds[w][qo];

    floatx4 acc[4][4];                // [i-sub][f-block], 64 VGPRs
#pragma unroll
    for (int sub = 0; sub < 4; ++sub)
#pragma unroll
        for (int K = 0; K < 4; ++K)
            acc[sub][K] = (floatx4){0.f, 0.f, 0.f, 0.f};
    float ls[4] = {0.f, 0.f, 0.f, 0.f};

#pragma unroll
    for (int jt = 0; jt < 8; ++jt) {              // 8 iters x 32 j per wave
        const int o = jt * 32;                    // static element offset
        floatx4 stA = *(const floatx4*)(stp + o);
        floatx4 stB = *(const floatx4*)(stp + o + 4);
        bf16x8 bf[4];
#pragma unroll
        for (int K = 0; K < 4; ++K)
            bf[K] = *(const bf16x8*)(ptr_f[K] + o);

#pragma unroll
        for (int sub = 0; sub < 4; ++sub) {
            floatx4 ajA = *(const floatx4*)(adj_s[sub] + o);
            floatx4 ajB = *(const floatx4*)(adj_s[sub] + o + 4);
            union { bf16x8 v; unsigned int u[4]; } a0;
            float wv[8];
#pragma unroll
            for (int e = 0; e < 8; ++e) {
                float stv = (e < 4) ? stA[e] : stB[e - 4];
                float av  = (e < 4) ? ajA[e] : ajB[e - 4];
                float s = ssv[sub] + stv;
                s = fmaxf(s, 0.2f * s);           // leaky_relu(0.2)
                float u = (s + av) * LOG2E;
                wv[e] = EXP2(u);
                ls[sub] += wv[e];
            }
            a0.u[0] = pack_bf16(wv[0], wv[1]);
            a0.u[1] = pack_bf16(wv[2], wv[3]);
            a0.u[2] = pack_bf16(wv[4], wv[5]);
            a0.u[3] = pack_bf16(wv[6], wv[7]);
#pragma unroll
            for (int K = 0; K < 4; ++K)
                acc[sub][K] = __builtin_amdgcn_mfma_f32_16x16x32_bf16(
                    a0.v, bf[K], acc[sub][K], 0, 0, 0);
        }
    }

    // wave-local row-sums over quads (row = sub*16 + l16 in A-layout)
#pragma unroll
    for (int sub = 0; sub < 4; ++sub) {
        ls[sub] += __shfl_xor(ls[sub], 16, 64);
        ls[sub] += __shfl_xor(ls[sub], 32, 64);
    }

    // epilogue: 4 chunks of 16 rows; 8-wave LDS reduction per chunk
#pragma unroll
    for (int sub = 0; sub < 4; ++sub) {
        __syncthreads();   // protect red[] from previous chunk's readers
#pragma unroll
        for (int K = 0; K < 4; ++K)
#pragma unroll
            for (int r = 0; r < 4; ++r)
                red[w][(quad * 4 + r) * RSTRIDE + K * 16 + l16] = acc[sub][K][r];
        if (quad == 0)
            red[w][16 * RSTRIDE + l16] = ls[sub];
        __syncthreads();
#pragma unroll
        for (int p = 0; p < 2; ++p) {
            int e   = tid + p * 512;
            int row = e >> 6;
            int col = e & 63;
            float s = 0.f, l = 0.f;
#pragma unroll
            for (int ww = 0; ww < 8; ++ww) {
                s += red[ww][row * RSTRIDE + col];
                l += red[ww][16 * RSTRIDE + row];
            }
            float v = s / l + bias[h * FO_ + col];
            v = (v > 0.f) ? v : expm1f(v);        // elu (fp32 out)
            out[((size_t)b * NN_ + i0 + sub * 16 + row) * D_ + h * FO_ + col] = v;
        }
    }
}

// ---------------------------------------------------------------------------
extern "C" void kernel_launch(void* const* d_in, const int* in_sizes, int n_in,
                              void* d_out, int out_size, void* d_ws, size_t ws_size,
                              hipStream_t stream) {
    const float* x     = (const float*)d_in[0];   // (4,2048,128) fp32
    const float* adj   = (const float*)d_in[1];   // (4,2048,2048) fp32
    const float* wproj = (const float*)d_in[2];   // (256,128) fp32
    const float* ssrc  = (const float*)d_in[3];   // (4,64) fp32
    const float* stgt  = (const float*)d_in[4];   // (4,64) fp32
    const float* bias  = (const float*)d_in[5];   // (256,) fp32
    float* out = (float*)d_out;                   // (4,2048,256) fp32

    // ws layout: PT slabs only (1 MiB per batch); 4 MiB -> single pass
    const size_t SLAB = (size_t)D_ * NN_ * 2;
    short* pt = (short*)d_ws;

    int nb = (int)(ws_size / SLAB);
    if (nb < 1) nb = 1;
    if (nb > 4) nb = 4;

    for (int bb0 = 0; bb0 < BN_; bb0 += nb) {
        int cnt = (BN_ - bb0 < nb) ? (BN_ - bb0) : nb;
        proj_kernel<<<dim3(NN_ / 256, H_, cnt), 256, 0, stream>>>(
            x, wproj, pt, bb0);
        attn_kernel<<<dim3(NN_ / 64, H_, cnt), 512, 0, stream>>>(
            adj, pt, ssrc, stgt, bias, out, bb0);
    }
}

// Round 8
// 205.592 us; speedup vs baseline: 1.0670x; 1.0670x over previous
//
#include <hip/hip_runtime.h>
#include <hip/hip_bf16.h>
#include <math.h>

// Problem constants (BN, N, FIN, FO, H) from the reference
#define BN_   4
#define NN_   2048
#define FIN_  128
#define FO_   64
#define H_    4
#define D_    256   // FO*H

typedef __attribute__((ext_vector_type(8))) short bf16x8;   // 8 bf16 = 4 VGPRs
typedef __attribute__((ext_vector_type(4))) float floatx4;  // MFMA C/D frag

#define LOG2E 1.4426950408889634f

#if __has_builtin(__builtin_amdgcn_exp2f)
#define EXP2(x) __builtin_amdgcn_exp2f(x)
#else
#define EXP2(x) exp2f(x)
#endif

__device__ __forceinline__ float bf2f(short u) {
    union { unsigned int i; float f; } v;
    v.i = ((unsigned int)(unsigned short)u) << 16;
    return v.f;
}
__device__ __forceinline__ short f2bf(float f) {
    union { float f; unsigned int u; } v; v.f = f;
    unsigned int r = v.u + 0x7fffu + ((v.u >> 16) & 1u);  // RNE
    return (short)(unsigned short)(r >> 16);
}

// pack two floats to two bf16 (RNE) in one dword; elem0 in low 16 bits
#if defined(__BF16_MANT_DIG__)
typedef __bf16 bfr2 __attribute__((ext_vector_type(2)));
__device__ __forceinline__ unsigned int pack_bf16(float a, float b) {
    union { bfr2 h; unsigned int u; } v;
    v.h = (bfr2){(__bf16)a, (__bf16)b};
    return v.u;
}
#else
__device__ __forceinline__ unsigned int pack_bf16(float a, float b) {
    return ((unsigned int)(unsigned short)f2bf(a)) |
           (((unsigned int)(unsigned short)f2bf(b)) << 16);
}
#endif

// load 8 consecutive fp32 and round to a bf16x8 MFMA fragment
__device__ __forceinline__ bf16x8 load8f(const float* __restrict__ p) {
    floatx4 a = *(const floatx4*)p;
    floatx4 b = *(const floatx4*)(p + 4);
    union { bf16x8 v; unsigned int u[4]; } r;
    r.u[0] = pack_bf16(a[0], a[1]);
    r.u[1] = pack_bf16(a[2], a[3]);
    r.u[2] = pack_bf16(b[0], b[1]);
    r.u[3] = pack_bf16(b[2], b[3]);
    return r.v;
}

// ---------------------------------------------------------------------------
// Kernel 1: PT[b_rel][h][f][j] = sum_c x[b,j,c] * W_proj[f*H+h, c]  (bf16)
// PT slab per batch: row index (b_rel*D_ + h*64 + f), j contiguous.
// MFMA 16x16x32 bf16: A[m=lane&15][k=quad*8+e]=W rows, B[n=lane&15][k]=x.
// ---------------------------------------------------------------------------
__global__ __launch_bounds__(256) void proj_kernel(
    const float* __restrict__ x,      // (BN, NN, FIN) fp32
    const float* __restrict__ wproj,  // (D, FIN) fp32
    short* __restrict__ pt,           // (nb*D, NN) bf16 slabs
    int b0)
{
    const int tid  = threadIdx.x;
    const int wave = tid >> 6;
    const int lane = tid & 63;
    const int l16  = lane & 15;
    const int quad = lane >> 4;

    const int b_rel = blockIdx.z;
    const int b  = b0 + b_rel;
    const int h  = blockIdx.y;            // D_/64 == H_, so y-block == head
    const int d0 = h * 64;
    const int j0 = blockIdx.x * 256 + wave * 64;

    floatx4 acc[4][4];
#pragma unroll
    for (int mi = 0; mi < 4; ++mi)
#pragma unroll
        for (int nj = 0; nj < 4; ++nj)
            acc[mi][nj] = (floatx4){0.f, 0.f, 0.f, 0.f};

#pragma unroll
    for (int kc = 0; kc < 4; ++kc) {
        const int c = kc * 32 + quad * 8;
        bf16x8 afr[4], bfr[4];
#pragma unroll
        for (int mi = 0; mi < 4; ++mi) {
            int f = (d0 + mi * 16 + l16) & 63;
            int srow = f * H_ + h;                // W_proj row (flat d = f*H+h)
            afr[mi] = load8f(wproj + srow * FIN_ + c);
        }
#pragma unroll
        for (int nj = 0; nj < 4; ++nj) {
            int j = j0 + nj * 16 + l16;
            bfr[nj] = load8f(x + ((size_t)b * NN_ + j) * FIN_ + c);
        }
#pragma unroll
        for (int mi = 0; mi < 4; ++mi)
#pragma unroll
            for (int nj = 0; nj < 4; ++nj)
                acc[mi][nj] = __builtin_amdgcn_mfma_f32_16x16x32_bf16(
                    afr[mi], bfr[nj], acc[mi][nj], 0, 0, 0);
    }

    // C/D layout: col(n=j) = lane&15, row(m=d') = quad*4 + reg
#pragma unroll
    for (int mi = 0; mi < 4; ++mi) {
#pragma unroll
        for (int r = 0; r < 4; ++r) {
            int dp = d0 + mi * 16 + quad * 4 + r;
            size_t base = ((size_t)b_rel * D_ + dp) * NN_;
#pragma unroll
            for (int nj = 0; nj < 4; ++nj) {
                int j = j0 + nj * 16 + l16;
                pt[base + j] = f2bf(acc[mi][nj][r]);
            }
        }
    }
}

// ---------------------------------------------------------------------------
// Kernel 2: fused attention, I-tile = 64. Block = 8 waves on the SAME
// (b, head, 64-row i-tile); waves split j (256 each). Each wave holds 4
// 16-row A-fragments (weights) sharing the same pt B-fragments (4x reuse).
// s_src / s_tgt recomputed in-block from PT -> no s workspace.
// __launch_bounds__(512, 2): 256-VGPR cap -> acc[4][4] (64) + ~100 arch
// VGPRs fit with NO spills (round 7 at (512,4)/128-cap spilled 83 MB of
// scratch writes per dispatch and serialized the loop). 1 block/CU, 8
// waves/CU -- rounds 4-7 showed occupancy 21-76% does not affect dur.
// ---------------------------------------------------------------------------
#define RSTRIDE 65   // LDS row stride (pad +1 col to break bank alignment)
#define WSLOT   (RSTRIDE * 16 + 16)   // 1056 floats per wave slot

__global__ __launch_bounds__(512, 2) void attn_kernel(
    const float* __restrict__ adj,    // (BN, NN, NN) fp32
    const short* __restrict__ pt,     // (nb*D, NN) bf16
    const float* __restrict__ ssrc,   // (H, FO) fp32
    const float* __restrict__ stgt,   // (H, FO) fp32
    const float* __restrict__ bias,   // (D,) fp32
    float* __restrict__ out,          // (BN, NN, D) fp32
    int b0)
{
    __shared__ float red[8][WSLOT];   // 33792 B (reduction scratch)
    __shared__ float st_lds[8][256];  // per-wave s_tgt slice (8 KiB)
    __shared__ float ss_lds[64];      // s_src for the i-tile

    const int tid  = threadIdx.x;
    const int w    = tid >> 6;        // wave = j-slice
    const int lane = tid & 63;
    const int l16  = lane & 15;
    const int quad = lane >> 4;

    const int b_rel = blockIdx.z;
    const int b  = b0 + b_rel;
    const int h  = blockIdx.y;
    const int i0 = blockIdx.x * 64;

    const short* pt_bh = pt + ((size_t)b_rel * D_ + h * FO_) * NN_;

    // my 4 f-rows' score weights (f = K*16 + l16)
    float stw[4], ssw[4];
#pragma unroll
    for (int K = 0; K < 4; ++K) {
        stw[K] = stgt[h * FO_ + K * 16 + l16];
        ssw[K] = ssrc[h * FO_ + K * 16 + l16];
    }

    // ---- preamble A: s_tgt for this wave's 256-j slice -> st_lds[w] ----
#pragma unroll
    for (int pj = 0; pj < 8; ++pj) {
        const int c = w * 256 + pj * 32 + quad * 8;
        bf16x8 p0 = *(const bf16x8*)(pt_bh + (size_t)(l16) * NN_ + c);
        bf16x8 p1 = *(const bf16x8*)(pt_bh + (size_t)(16 + l16) * NN_ + c);
        bf16x8 p2 = *(const bf16x8*)(pt_bh + (size_t)(32 + l16) * NN_ + c);
        bf16x8 p3 = *(const bf16x8*)(pt_bh + (size_t)(48 + l16) * NN_ + c);
#pragma unroll
        for (int e = 0; e < 8; ++e) {
            float t = stw[0] * bf2f(p0[e]) + stw[1] * bf2f(p1[e])
                    + stw[2] * bf2f(p2[e]) + stw[3] * bf2f(p3[e]);
            t += __shfl_xor(t, 1, 64); t += __shfl_xor(t, 2, 64);
            t += __shfl_xor(t, 4, 64); t += __shfl_xor(t, 8, 64);
            if (l16 == 0) st_lds[w][pj * 32 + quad * 8 + e] = t;
        }
    }

    // ---- preamble B: s_src for the 64 i-rows (waves 0,1) -> ss_lds ----
    if (w < 2) {
        const int c = i0 + w * 32 + quad * 8;
        bf16x8 p0 = *(const bf16x8*)(pt_bh + (size_t)(l16) * NN_ + c);
        bf16x8 p1 = *(const bf16x8*)(pt_bh + (size_t)(16 + l16) * NN_ + c);
        bf16x8 p2 = *(const bf16x8*)(pt_bh + (size_t)(32 + l16) * NN_ + c);
        bf16x8 p3 = *(const bf16x8*)(pt_bh + (size_t)(48 + l16) * NN_ + c);
#pragma unroll
        for (int e = 0; e < 8; ++e) {
            float t = ssw[0] * bf2f(p0[e]) + ssw[1] * bf2f(p1[e])
                    + ssw[2] * bf2f(p2[e]) + ssw[3] * bf2f(p3[e]);
            t += __shfl_xor(t, 1, 64); t += __shfl_xor(t, 2, 64);
            t += __shfl_xor(t, 4, 64); t += __shfl_xor(t, 8, 64);
            if (l16 == 0) ss_lds[w * 32 + quad * 8 + e] = t;
        }
    }
    __syncthreads();

    // per-lane s_src for my 4 sub-tiles (row = sub*16 + l16)
    float ssv[4];
#pragma unroll
    for (int sub = 0; sub < 4; ++sub)
        ssv[sub] = ss_lds[sub * 16 + l16];

    // pre-offset global bases (wave j-slice + quad offset folded in)
    const int qo = quad * 8;
    const float* adj_s[4];
#pragma unroll
    for (int sub = 0; sub < 4; ++sub)
        adj_s[sub] = adj + ((size_t)b * NN_ + i0 + sub * 16 + l16) * NN_ + w * 256 + qo;
    const short* ptr_f[4];
#pragma unroll
    for (int K = 0; K < 4; ++K)
        ptr_f[K] = pt_bh + (size_t)(K * 16 + l16) * NN_ + w * 256 + qo;
    const float* stp = &st_lds[w][qo];

    floatx4 acc[4][4];                // [i-sub][f-block], 64 regs
#pragma unroll
    for (int sub = 0; sub < 4; ++sub)
#pragma unroll
        for (int K = 0; K < 4; ++K)
            acc[sub][K] = (floatx4){0.f, 0.f, 0.f, 0.f};
    float ls[4] = {0.f, 0.f, 0.f, 0.f};

#pragma unroll
    for (int jt = 0; jt < 8; ++jt) {              // 8 iters x 32 j per wave
        const int o = jt * 32;                    // static element offset
        floatx4 stA = *(const floatx4*)(stp + o);
        floatx4 stB = *(const floatx4*)(stp + o + 4);
        bf16x8 bf[4];
#pragma unroll
        for (int K = 0; K < 4; ++K)
            bf[K] = *(const bf16x8*)(ptr_f[K] + o);

#pragma unroll
        for (int sub = 0; sub < 4; ++sub) {
            floatx4 ajA = *(const floatx4*)(adj_s[sub] + o);
            floatx4 ajB = *(const floatx4*)(adj_s[sub] + o + 4);
            union { bf16x8 v; unsigned int u[4]; } a0;
            float wv[8];
#pragma unroll
            for (int e = 0; e < 8; ++e) {
                float stv = (e < 4) ? stA[e] : stB[e - 4];
                float av  = (e < 4) ? ajA[e] : ajB[e - 4];
                float s = ssv[sub] + stv;
                s = fmaxf(s, 0.2f * s);           // leaky_relu(0.2)
                float u = (s + av) * LOG2E;
                wv[e] = EXP2(u);
                ls[sub] += wv[e];
            }
            a0.u[0] = pack_bf16(wv[0], wv[1]);
            a0.u[1] = pack_bf16(wv[2], wv[3]);
            a0.u[2] = pack_bf16(wv[4], wv[5]);
            a0.u[3] = pack_bf16(wv[6], wv[7]);
#pragma unroll
            for (int K = 0; K < 4; ++K)
                acc[sub][K] = __builtin_amdgcn_mfma_f32_16x16x32_bf16(
                    a0.v, bf[K], acc[sub][K], 0, 0, 0);
        }
    }

    // wave-local row-sums over quads (row = sub*16 + l16 in A-layout)
#pragma unroll
    for (int sub = 0; sub < 4; ++sub) {
        ls[sub] += __shfl_xor(ls[sub], 16, 64);
        ls[sub] += __shfl_xor(ls[sub], 32, 64);
    }

    // epilogue: 4 chunks of 16 rows; 8-wave LDS reduction per chunk
#pragma unroll
    for (int sub = 0; sub < 4; ++sub) {
        __syncthreads();   // protect red[] from previous chunk's readers
#pragma unroll
        for (int K = 0; K < 4; ++K)
#pragma unroll
            for (int r = 0; r < 4; ++r)
                red[w][(quad * 4 + r) * RSTRIDE + K * 16 + l16] = acc[sub][K][r];
        if (quad == 0)
            red[w][16 * RSTRIDE + l16] = ls[sub];
        __syncthreads();
#pragma unroll
        for (int p = 0; p < 2; ++p) {
            int e   = tid + p * 512;
            int row = e >> 6;
            int col = e & 63;
            float s = 0.f, l = 0.f;
#pragma unroll
            for (int ww = 0; ww < 8; ++ww) {
                s += red[ww][row * RSTRIDE + col];
                l += red[ww][16 * RSTRIDE + row];
            }
            float v = s / l + bias[h * FO_ + col];
            v = (v > 0.f) ? v : expm1f(v);        // elu (fp32 out)
            out[((size_t)b * NN_ + i0 + sub * 16 + row) * D_ + h * FO_ + col] = v;
        }
    }
}

// ---------------------------------------------------------------------------
extern "C" void kernel_launch(void* const* d_in, const int* in_sizes, int n_in,
                              void* d_out, int out_size, void* d_ws, size_t ws_size,
                              hipStream_t stream) {
    const float* x     = (const float*)d_in[0];   // (4,2048,128) fp32
    const float* adj   = (const float*)d_in[1];   // (4,2048,2048) fp32
    const float* wproj = (const float*)d_in[2];   // (256,128) fp32
    const float* ssrc  = (const float*)d_in[3];   // (4,64) fp32
    const float* stgt  = (const float*)d_in[4];   // (4,64) fp32
    const float* bias  = (const float*)d_in[5];   // (256,) fp32
    float* out = (float*)d_out;                   // (4,2048,256) fp32

    // ws layout: PT slabs only (1 MiB per batch)
    const size_t SLAB = (size_t)D_ * NN_ * 2;
    short* pt = (short*)d_ws;

    int nb = (int)(ws_size / SLAB);
    if (nb < 1) nb = 1;
    if (nb > 4) nb = 4;

    for (int bb0 = 0; bb0 < BN_; bb0 += nb) {
        int cnt = (BN_ - bb0 < nb) ? (BN_ - bb0) : nb;
        proj_kernel<<<dim3(NN_ / 256, H_, cnt), 256, 0, stream>>>(
            x, wproj, pt, bb0);
        attn_kernel<<<dim3(NN_ / 64, H_, cnt), 512, 0, stream>>>(
            adj, pt, ssrc, stgt, bias, out, bb0);
    }
}